// Round 7
// baseline (1386.009 us; speedup 1.0000x reference)
//
#include <hip/hip_runtime.h>
#include <hip/hip_bf16.h>

// EntityTable: B=16,T=2048,D=1024,N_E=8,D_E=64
// Phase A (parallel): hp = h@Wi^T + bi ; logits = h@ek^T/32 ; w = softmax(logits)
//                     P  = W_ih @ hp   (entity-independent input-gate projection)
// Phase B (sequential scan over T): per cell (b,n):
//   gx_k = w*P_k + b_ih_k ; gh_k = W_hh[k]·s + b_hh_k
//   r=sig(gx0+gh0) z=sig(gx1+gh1) n=tanh(gx2 + r*gh2) ; s' = (1-z)n + z s
//
// Round-7 scan: fp32 (f16 recurrence failed accuracy in r6). 3 waves per cell,
// one GATE per wave (32 pk_fma = 128 cyc MAC issue/wave vs 384 single-wave).
// Private per-wave LDS state copies (own-write/own-read, no cross-wave order),
// redundant activation in all waves; cross-wave exchange = 4 floats/lane
// {rr, zz (pre-sigmoided), u, v} via double-buffered LDS + ONE raw s_barrier
// with lgkmcnt-only drain (global prefetches stay in flight).

constexpr int B_  = 16;
constexpr int T_  = 2048;
constexpr int D_  = 1024;
constexpr int NE  = 8;
constexpr int DE  = 64;
constexpr int G3  = 192;            // 3*DE
constexpr int ROWS = B_ * T_;       // 32768
constexpr int OUT1OFF = ROWS * NE * DE;  // 16777216

typedef __attribute__((ext_vector_type(2))) float f32x2;
typedef __attribute__((ext_vector_type(4))) float f32x4;

__device__ __forceinline__ void pkacc(f32x2& acc, f32x2 w, f32x2 s) {
    asm("v_pk_fma_f32 %0, %1, %2, %0" : "+v"(acc) : "v"(w), "v"(s));
}

// ---------------- Kernel T: transpose Wi -> WT4 ----------------
__global__ __launch_bounds__(256) void wt_kernel(
    const float* __restrict__ Wi, float* __restrict__ WT4)
{
    const int o  = blockIdx.x;     // 64 blocks
    const int dq = threadIdx.x;    // 256 threads
    const float4 v = *(const float4*)&Wi[o * D_ + dq * 4];
    *(float4*)&WT4[(dq * 64 + o) * 4] = v;
}

// ---------------- Kernel A: projection + routing + P ----------------
constexpr int RPB = 32;   // rows per block
constexpr int CH  = 128;  // K-chunk

__global__ __launch_bounds__(256) void proj_kernel(
    const float* __restrict__ h,   const float* __restrict__ ek,
    const float* __restrict__ WT4, const float* __restrict__ bi,
    const float* __restrict__ Wih,
    float* __restrict__ Pout, float* __restrict__ wout)
{
    __shared__ float hch[RPB][CH];   // 16 KB
    __shared__ float hp[RPB][DE];    // 8 KB
    __shared__ float lg[RPB][NE];    // 1 KB

    const int tid = threadIdx.x;
    const int brow = blockIdx.x * RPB;
    const int w = tid >> 6;          // wave 0..3
    const int o = tid & 63;          // lane = output index for hp
    const int n  = o & 7;            // entity for logit partial
    const int sl = o >> 3;           // K-slice for logit partial

    float acc[8], accl[8];
#pragma unroll
    for (int r = 0; r < 8; ++r) { acc[r] = 0.f; accl[r] = 0.f; }

    for (int kc = 0; kc < D_; kc += CH) {
        __syncthreads();
#pragma unroll
        for (int i = 0; i < 4; ++i) {
            int idx = tid + i * 256;
            int lr = idx >> 5;
            int c4 = (idx & 31) * 4;
            *(float4*)&hch[lr][c4] =
                *(const float4*)&h[(size_t)(brow + lr) * D_ + kc + c4];
        }
        __syncthreads();

        for (int d4 = 0; d4 < CH / 4; ++d4) {
            const float4 wt = *(const float4*)&WT4[((kc >> 2) + d4) * 256 + (o << 2)];
#pragma unroll
            for (int r = 0; r < 8; ++r) {
                const float4 h4 = *(const float4*)&hch[w * 8 + r][d4 * 4];
                acc[r] = fmaf(wt.x, h4.x,
                         fmaf(wt.y, h4.y,
                         fmaf(wt.z, h4.z,
                         fmaf(wt.w, h4.w, acc[r]))));
            }
        }
#pragma unroll
        for (int i4 = 0; i4 < 4; ++i4) {
            const int dl = sl * 16 + i4 * 4;
            const float4 e4 = *(const float4*)&ek[n * D_ + kc + dl];
#pragma unroll
            for (int r = 0; r < 8; ++r) {
                const float4 h4 = *(const float4*)&hch[w * 8 + r][dl];
                accl[r] = fmaf(e4.x, h4.x,
                          fmaf(e4.y, h4.y,
                          fmaf(e4.z, h4.z,
                          fmaf(e4.w, h4.w, accl[r]))));
            }
        }
    }

    const float biv = bi[o];
#pragma unroll
    for (int r = 0; r < 8; ++r) hp[w * 8 + r][o] = acc[r] + biv;

#pragma unroll
    for (int r = 0; r < 8; ++r) {
        accl[r] += __shfl_xor(accl[r], 8);
        accl[r] += __shfl_xor(accl[r], 16);
        accl[r] += __shfl_xor(accl[r], 32);
    }
    if (sl == 0) {
#pragma unroll
        for (int r = 0; r < 8; ++r) lg[w * 8 + r][n] = accl[r] * 0.03125f;
    }
    __syncthreads();

    if (tid < RPB) {
        const int lr = tid;
        float v[NE];
        float m = -1e30f;
#pragma unroll
        for (int e = 0; e < NE; ++e) { v[e] = lg[lr][e]; m = fmaxf(m, v[e]); }
        float s = 0.f;
#pragma unroll
        for (int e = 0; e < NE; ++e) { v[e] = __expf(v[e] - m); s += v[e]; }
        const float inv = 1.f / s;
#pragma unroll
        for (int e = 0; e < NE; ++e)
            wout[(size_t)(brow + lr) * NE + e] = v[e] * inv;
    }

    if (tid < G3) {
        const int k = tid;
        for (int lr0 = 0; lr0 < RPB; lr0 += 8) {
            float pacc[8];
#pragma unroll
            for (int r = 0; r < 8; ++r) pacc[r] = 0.f;
            for (int d4 = 0; d4 < DE / 4; ++d4) {
                const float4 wv = *(const float4*)&Wih[k * DE + d4 * 4];
#pragma unroll
                for (int r = 0; r < 8; ++r) {
                    const float4 h4 = *(const float4*)&hp[lr0 + r][d4 * 4];
                    pacc[r] = fmaf(wv.x, h4.x,
                              fmaf(wv.y, h4.y,
                              fmaf(wv.z, h4.z,
                              fmaf(wv.w, h4.w, pacc[r]))));
                }
            }
#pragma unroll
            for (int r = 0; r < 8; ++r)
                Pout[(size_t)(brow + lr0 + r) * G3 + k] = pacc[r];
        }
    }
}

// ---------------- Kernel B: 3-wave gate-split GRU scan ----------------
// 128 blocks x 192 threads. Wave wid owns gate wid (rows wid*64+j).
// weight row q-th f32x4: Whh[(base)*64 + 4q], base = wid*64 + j (SSA names)
#define DW(q) const f32x4 w##q = *(const f32x4*)&Whh[(size_t)base * 64 + 4 * (q)];
#define DW16() \
    DW(0)  DW(1)  DW(2)  DW(3)  DW(4)  DW(5)  DW(6)  DW(7) \
    DW(8)  DW(9)  DW(10) DW(11) DW(12) DW(13) DW(14) DW(15)

#define MACQ(q) { \
    const f32x4 s4 = *(const f32x4*)&s_own[wid][4 * (q)]; \
    pkacc(acc, w##q.lo, s4.lo); pkacc(acc, w##q.hi, s4.hi); }
#define MAC16() \
    MACQ(0)  MACQ(1)  MACQ(2)  MACQ(3)  MACQ(4)  MACQ(5)  MACQ(6)  MACQ(7) \
    MACQ(8)  MACQ(9)  MACQ(10) MACQ(11) MACQ(12) MACQ(13) MACQ(14) MACQ(15)

__global__ __launch_bounds__(192, 1) void scan_kernel(
    const float* __restrict__ P,   const float* __restrict__ route,
    const float* __restrict__ Whh, const float* __restrict__ bih,
    const float* __restrict__ bhh, const float* __restrict__ e0,
    float* __restrict__ out, int write1)
{
    __shared__ __align__(16) float s_own[3][DE];   // per-wave private state copy
    __shared__ float ex[2][4][DE];                 // dbuf exchange {rr,zz,u,v}

    // XCD co-location (kept from r5: halves scan FETCH, time-neutral)
    const int g   = blockIdx.x;          // 0..127
    const int xcd = g & 7;
    const int ii  = g >> 3;              // 0..15
    const int b   = xcd + 8 * (ii & 1);
    const int n   = ii >> 1;
    const int tid = threadIdx.x;
    const int wid = tid >> 6;            // 0=r, 1=z, 2=n gate
    const int j   = tid & 63;
    const int base = wid * DE + j;       // this lane's gate row

    DW16()                               // 16 named f32x4 = 64 VGPR weights

    // biases: waves 0/1 use combined (bih+bhh); wave 2 keeps them split
    const float Bc   = bih[base] + bhh[base];
    const float bin_ = bih[base];        // used by wave 2 only
    const float bhn_ = bhh[base];        // used by wave 2 only

    const size_t row0 = (size_t)b * T_;
    float s_reg = e0[n * DE + j];
    s_own[wid][j] = s_reg;               // own-wave write; own-wave reads (lgkm-ordered)

    const float* Pb = P + row0 * G3 + base;   // this wave's gate rows, + t*G3
    const float* rb = route + row0 * NE + n;  // + t*NE
    float* op = out + row0 * (size_t)(NE * DE) + n * DE + j;

    // prefetch depth 2
    float p0 = Pb[0], p1 = Pb[G3];
    float wv0 = rb[0], wv1 = rb[NE];

    int buf = 0;

    for (int t = 0; t < T_; ++t) {
        const int tn = (t + 2 < T_) ? (t + 2) : t;     // clamp tail (reload, harmless)
        const float pnx  = Pb[(size_t)tn * G3];
        const float wnx  = rb[(size_t)tn * NE];

        // ---- this wave's gate dot over its private s copy ----
        f32x2 acc = {0.f, 0.f};
        MAC16()
        const float gh = acc.x + acc.y;
        const float gx = fmaf(wv0, p0, (wid == 2) ? bin_ : Bc);

        // ---- pre-barrier: waves 0/1 fold their sigmoid; wave 2 ships u,v ----
        if (wid == 2) {
            ex[buf][2][j] = gx;           // u = gx_n + b_ih,n
            ex[buf][3][j] = gh + bhn_;    // v = gh_n + b_hh,n
        } else {
            const float sg = __builtin_amdgcn_rcpf(1.f + __expf(-(gx + gh)));
            ex[buf][wid][j] = sg;         // rr (wid 0) / zz (wid 1)
        }

        asm volatile("s_waitcnt lgkmcnt(0)" ::: "memory");
        __builtin_amdgcn_s_barrier();

        // ---- redundant activation (all waves) ----
        const float rr = ex[buf][0][j];
        const float zz = ex[buf][1][j];
        const float u  = ex[buf][2][j];
        const float v  = ex[buf][3][j];
        const float x  = fmaf(rr, v, u);
        const float nn = fmaf(2.f, __builtin_amdgcn_rcpf(1.f + __expf(-2.f * x)), -1.f);
        const float snew = fmaf(zz, s_reg - nn, nn);   // (1-z)n + z s
        s_reg = snew;
        s_own[wid][j] = snew;             // own copy for next step's dot

        if (wid == 0) op[(size_t)t * (NE * DE)] = snew;
        else if (write1 && wid == 1) op[OUT1OFF + (size_t)t * (NE * DE)] = snew;

        p0 = p1; p1 = pnx; wv0 = wv1; wv1 = wnx;
        buf ^= 1;
    }
}

// ---------------- Kernel C: replicate out0 -> out1 (stash path) ----------------
__global__ __launch_bounds__(256) void copy_kernel(
    const float4* __restrict__ src, float4* __restrict__ dst, int n4)
{
    int i = blockIdx.x * 256 + threadIdx.x;
    const int stride = gridDim.x * 256;
    for (; i < n4; i += stride) dst[i] = src[i];
}

extern "C" void kernel_launch(void* const* d_in, const int* in_sizes, int n_in,
                              void* d_out, int out_size, void* d_ws, size_t ws_size,
                              hipStream_t stream) {
    const float* h_seq = (const float*)d_in[0];
    const float* ek    = (const float*)d_in[1];
    const float* Wi    = (const float*)d_in[2];
    const float* bi    = (const float*)d_in[3];
    const float* Wih   = (const float*)d_in[4];
    const float* Whh   = (const float*)d_in[5];
    const float* bih   = (const float*)d_in[6];
    const float* bhh   = (const float*)d_in[7];
    const float* e0    = (const float*)d_in[8];
    float* out = (float*)d_out;

    const size_t need = (size_t)ROWS * (G3 + NE) * sizeof(float)
                      + (size_t)DE * D_ * sizeof(float);  // ~26.5 MB
    float* wbuf;
    int write1;
    if (ws_size >= need) {
        wbuf = (float*)d_ws;
        write1 = 1;                    // scan writes both output copies
    } else {
        wbuf = out + OUT1OFF;          // stash in out1; copy at the end
        write1 = 0;
    }
    float* Pbuf = wbuf + (size_t)ROWS * NE;
    float* WT4  = Pbuf + (size_t)ROWS * G3;

    wt_kernel<<<DE, 256, 0, stream>>>(Wi, WT4);
    proj_kernel<<<ROWS / RPB, 256, 0, stream>>>(h_seq, ek, WT4, bi, Wih, Pbuf, wbuf);
    scan_kernel<<<B_ * NE, 192, 0, stream>>>(Pbuf, wbuf, Whh, bih, bhh, e0, out, write1);

    if (!write1) {
        copy_kernel<<<2048, 256, 0, stream>>>((const float4*)out,
                                              (float4*)(out + OUT1OFF), OUT1OFF / 4);
    }
}

// Round 8
// 1384.589 us; speedup vs baseline: 1.0010x; 1.0010x over previous
//
#include <hip/hip_runtime.h>
#include <hip/hip_bf16.h>

// EntityTable: B=16,T=2048,D=1024,N_E=8,D_E=64
// Phase A (parallel): hp = h@Wi^T + bi ; logits = h@ek^T/32 ; w = softmax(logits)
//                     P  = W_ih @ hp   (entity-independent input-gate projection)
// Phase B (sequential scan over T): per cell (b,n):
//   gx_k = w*P_k + b_ih_k ; gh_k = W_hh[k]·s + b_hh_k
//   r=sig(gx0+gh0) z=sig(gx1+gh1) n=tanh(gx2 + r*gh2) ; s' = (1-z)n + z s
//
// Round-8 scan: r7's 3-wave gate-split + ASM KEEP-ALIVE on the 16 weight
// f32x4s. r7's VGPR_Count=48 proved the compiler sank the loop-invariant
// weight loads into the loop (per-step L1 reloads + vmcnt drains coupling
// prefetch latency onto the critical path). The empty asm "+v" pins make the
// values non-rematerializable -> must stay register-resident.

constexpr int B_  = 16;
constexpr int T_  = 2048;
constexpr int D_  = 1024;
constexpr int NE  = 8;
constexpr int DE  = 64;
constexpr int G3  = 192;            // 3*DE
constexpr int ROWS = B_ * T_;       // 32768
constexpr int OUT1OFF = ROWS * NE * DE;  // 16777216

typedef __attribute__((ext_vector_type(2))) float f32x2;
typedef __attribute__((ext_vector_type(4))) float f32x4;

__device__ __forceinline__ void pkacc(f32x2& acc, f32x2 w, f32x2 s) {
    asm("v_pk_fma_f32 %0, %1, %2, %0" : "+v"(acc) : "v"(w), "v"(s));
}

// ---------------- Kernel T: transpose Wi -> WT4 ----------------
__global__ __launch_bounds__(256) void wt_kernel(
    const float* __restrict__ Wi, float* __restrict__ WT4)
{
    const int o  = blockIdx.x;     // 64 blocks
    const int dq = threadIdx.x;    // 256 threads
    const float4 v = *(const float4*)&Wi[o * D_ + dq * 4];
    *(float4*)&WT4[(dq * 64 + o) * 4] = v;
}

// ---------------- Kernel A: projection + routing + P ----------------
constexpr int RPB = 32;   // rows per block
constexpr int CH  = 128;  // K-chunk

__global__ __launch_bounds__(256) void proj_kernel(
    const float* __restrict__ h,   const float* __restrict__ ek,
    const float* __restrict__ WT4, const float* __restrict__ bi,
    const float* __restrict__ Wih,
    float* __restrict__ Pout, float* __restrict__ wout)
{
    __shared__ float hch[RPB][CH];   // 16 KB
    __shared__ float hp[RPB][DE];    // 8 KB
    __shared__ float lg[RPB][NE];    // 1 KB

    const int tid = threadIdx.x;
    const int brow = blockIdx.x * RPB;
    const int w = tid >> 6;          // wave 0..3
    const int o = tid & 63;          // lane = output index for hp
    const int n  = o & 7;            // entity for logit partial
    const int sl = o >> 3;           // K-slice for logit partial

    float acc[8], accl[8];
#pragma unroll
    for (int r = 0; r < 8; ++r) { acc[r] = 0.f; accl[r] = 0.f; }

    for (int kc = 0; kc < D_; kc += CH) {
        __syncthreads();
#pragma unroll
        for (int i = 0; i < 4; ++i) {
            int idx = tid + i * 256;
            int lr = idx >> 5;
            int c4 = (idx & 31) * 4;
            *(float4*)&hch[lr][c4] =
                *(const float4*)&h[(size_t)(brow + lr) * D_ + kc + c4];
        }
        __syncthreads();

        for (int d4 = 0; d4 < CH / 4; ++d4) {
            const float4 wt = *(const float4*)&WT4[((kc >> 2) + d4) * 256 + (o << 2)];
#pragma unroll
            for (int r = 0; r < 8; ++r) {
                const float4 h4 = *(const float4*)&hch[w * 8 + r][d4 * 4];
                acc[r] = fmaf(wt.x, h4.x,
                         fmaf(wt.y, h4.y,
                         fmaf(wt.z, h4.z,
                         fmaf(wt.w, h4.w, acc[r]))));
            }
        }
#pragma unroll
        for (int i4 = 0; i4 < 4; ++i4) {
            const int dl = sl * 16 + i4 * 4;
            const float4 e4 = *(const float4*)&ek[n * D_ + kc + dl];
#pragma unroll
            for (int r = 0; r < 8; ++r) {
                const float4 h4 = *(const float4*)&hch[w * 8 + r][dl];
                accl[r] = fmaf(e4.x, h4.x,
                          fmaf(e4.y, h4.y,
                          fmaf(e4.z, h4.z,
                          fmaf(e4.w, h4.w, accl[r]))));
            }
        }
    }

    const float biv = bi[o];
#pragma unroll
    for (int r = 0; r < 8; ++r) hp[w * 8 + r][o] = acc[r] + biv;

#pragma unroll
    for (int r = 0; r < 8; ++r) {
        accl[r] += __shfl_xor(accl[r], 8);
        accl[r] += __shfl_xor(accl[r], 16);
        accl[r] += __shfl_xor(accl[r], 32);
    }
    if (sl == 0) {
#pragma unroll
        for (int r = 0; r < 8; ++r) lg[w * 8 + r][n] = accl[r] * 0.03125f;
    }
    __syncthreads();

    if (tid < RPB) {
        const int lr = tid;
        float v[NE];
        float m = -1e30f;
#pragma unroll
        for (int e = 0; e < NE; ++e) { v[e] = lg[lr][e]; m = fmaxf(m, v[e]); }
        float s = 0.f;
#pragma unroll
        for (int e = 0; e < NE; ++e) { v[e] = __expf(v[e] - m); s += v[e]; }
        const float inv = 1.f / s;
#pragma unroll
        for (int e = 0; e < NE; ++e)
            wout[(size_t)(brow + lr) * NE + e] = v[e] * inv;
    }

    if (tid < G3) {
        const int k = tid;
        for (int lr0 = 0; lr0 < RPB; lr0 += 8) {
            float pacc[8];
#pragma unroll
            for (int r = 0; r < 8; ++r) pacc[r] = 0.f;
            for (int d4 = 0; d4 < DE / 4; ++d4) {
                const float4 wv = *(const float4*)&Wih[k * DE + d4 * 4];
#pragma unroll
                for (int r = 0; r < 8; ++r) {
                    const float4 h4 = *(const float4*)&hp[lr0 + r][d4 * 4];
                    pacc[r] = fmaf(wv.x, h4.x,
                              fmaf(wv.y, h4.y,
                              fmaf(wv.z, h4.z,
                              fmaf(wv.w, h4.w, pacc[r]))));
                }
            }
#pragma unroll
            for (int r = 0; r < 8; ++r)
                Pout[(size_t)(brow + lr0 + r) * G3 + k] = pacc[r];
        }
    }
}

// ---------------- Kernel B: 3-wave gate-split GRU scan (resident weights) ----------------
// 128 blocks x 192 threads. Wave wid owns gate wid (rows wid*64+j).
#define DW(q) f32x4 w##q = *(const f32x4*)&Whh[(size_t)base * 64 + 4 * (q)];
#define DW16() \
    DW(0)  DW(1)  DW(2)  DW(3)  DW(4)  DW(5)  DW(6)  DW(7) \
    DW(8)  DW(9)  DW(10) DW(11) DW(12) DW(13) DW(14) DW(15)

// keep-alive: pin each weight value in arch VGPRs (non-rematerializable)
#define KA(q) asm volatile("" : "+v"(w##q));
#define KA16() \
    KA(0)  KA(1)  KA(2)  KA(3)  KA(4)  KA(5)  KA(6)  KA(7) \
    KA(8)  KA(9)  KA(10) KA(11) KA(12) KA(13) KA(14) KA(15)

#define MACQ(q) { \
    const f32x4 s4 = *(const f32x4*)&s_own[wid][4 * (q)]; \
    pkacc(acc, w##q.lo, s4.lo); pkacc(acc, w##q.hi, s4.hi); }
#define MAC16() \
    MACQ(0)  MACQ(1)  MACQ(2)  MACQ(3)  MACQ(4)  MACQ(5)  MACQ(6)  MACQ(7) \
    MACQ(8)  MACQ(9)  MACQ(10) MACQ(11) MACQ(12) MACQ(13) MACQ(14) MACQ(15)

__global__ __launch_bounds__(192, 1) void scan_kernel(
    const float* __restrict__ P,   const float* __restrict__ route,
    const float* __restrict__ Whh, const float* __restrict__ bih,
    const float* __restrict__ bhh, const float* __restrict__ e0,
    float* __restrict__ out, int write1)
{
    __shared__ __align__(16) float s_own[3][DE];   // per-wave private state copy
    __shared__ float ex[2][4][DE];                 // dbuf exchange {rr,zz,u,v}

    // XCD co-location (halves scan FETCH, time-neutral)
    const int g   = blockIdx.x;          // 0..127
    const int xcd = g & 7;
    const int ii  = g >> 3;              // 0..15
    const int b   = xcd + 8 * (ii & 1);
    const int n   = ii >> 1;
    const int tid = threadIdx.x;
    const int wid = tid >> 6;            // 0=r, 1=z, 2=n gate
    const int j   = tid & 63;
    const int base = wid * DE + j;       // this lane's gate row

    DW16()                               // 16 f32x4 = 64 VGPR weights
    KA16()                               // pin resident (r7: compiler sank these)

    // biases: waves 0/1 use combined (bih+bhh); wave 2 keeps them split
    const float Bc   = bih[base] + bhh[base];
    const float bin_ = bih[base];        // wave 2 only
    const float bhn_ = bhh[base];        // wave 2 only

    const size_t row0 = (size_t)b * T_;
    float s_reg = e0[n * DE + j];
    s_own[wid][j] = s_reg;               // own-wave write/read (lgkm-ordered)

    const float* Pb = P + row0 * G3 + base;   // this wave's gate rows, + t*G3
    const float* rb = route + row0 * NE + n;  // + t*NE
    float* op = out + row0 * (size_t)(NE * DE) + n * DE + j;

    // prefetch depth 2
    float p0 = Pb[0], p1 = Pb[G3];
    float wv0 = rb[0], wv1 = rb[NE];

    int buf = 0;

    for (int t = 0; t < T_; ++t) {
        const int tn = (t + 2 < T_) ? (t + 2) : t;     // clamp tail
        const float pnx  = Pb[(size_t)tn * G3];
        const float wnx  = rb[(size_t)tn * NE];

        // ---- this wave's gate dot over its private s copy ----
        f32x2 acc = {0.f, 0.f};
        MAC16()
        const float gh = acc.x + acc.y;
        const float gx = fmaf(wv0, p0, (wid == 2) ? bin_ : Bc);

        // ---- pre-barrier: waves 0/1 fold their sigmoid; wave 2 ships u,v ----
        if (wid == 2) {
            ex[buf][2][j] = gx;           // u = gx_n + b_ih,n
            ex[buf][3][j] = gh + bhn_;    // v = gh_n + b_hh,n
        } else {
            const float sg = __builtin_amdgcn_rcpf(1.f + __expf(-(gx + gh)));
            ex[buf][wid][j] = sg;         // rr (wid 0) / zz (wid 1)
        }

        asm volatile("s_waitcnt lgkmcnt(0)" ::: "memory");
        __builtin_amdgcn_s_barrier();

        // ---- redundant activation (all waves) ----
        const float rr = ex[buf][0][j];
        const float zz = ex[buf][1][j];
        const float u  = ex[buf][2][j];
        const float v  = ex[buf][3][j];
        const float x  = fmaf(rr, v, u);
        const float nn = fmaf(2.f, __builtin_amdgcn_rcpf(1.f + __expf(-2.f * x)), -1.f);
        const float snew = fmaf(zz, s_reg - nn, nn);   // (1-z)n + z s
        s_reg = snew;
        s_own[wid][j] = snew;             // own copy for next step's dot

        if (wid == 0) op[(size_t)t * (NE * DE)] = snew;
        else if (write1 && wid == 1) op[OUT1OFF + (size_t)t * (NE * DE)] = snew;

        p0 = p1; p1 = pnx; wv0 = wv1; wv1 = wnx;
        buf ^= 1;
    }
}

// ---------------- Kernel C: replicate out0 -> out1 (stash path) ----------------
__global__ __launch_bounds__(256) void copy_kernel(
    const float4* __restrict__ src, float4* __restrict__ dst, int n4)
{
    int i = blockIdx.x * 256 + threadIdx.x;
    const int stride = gridDim.x * 256;
    for (; i < n4; i += stride) dst[i] = src[i];
}

extern "C" void kernel_launch(void* const* d_in, const int* in_sizes, int n_in,
                              void* d_out, int out_size, void* d_ws, size_t ws_size,
                              hipStream_t stream) {
    const float* h_seq = (const float*)d_in[0];
    const float* ek    = (const float*)d_in[1];
    const float* Wi    = (const float*)d_in[2];
    const float* bi    = (const float*)d_in[3];
    const float* Wih   = (const float*)d_in[4];
    const float* Whh   = (const float*)d_in[5];
    const float* bih   = (const float*)d_in[6];
    const float* bhh   = (const float*)d_in[7];
    const float* e0    = (const float*)d_in[8];
    float* out = (float*)d_out;

    const size_t need = (size_t)ROWS * (G3 + NE) * sizeof(float)
                      + (size_t)DE * D_ * sizeof(float);  // ~26.5 MB
    float* wbuf;
    int write1;
    if (ws_size >= need) {
        wbuf = (float*)d_ws;
        write1 = 1;                    // scan writes both output copies
    } else {
        wbuf = out + OUT1OFF;          // stash in out1; copy at the end
        write1 = 0;
    }
    float* Pbuf = wbuf + (size_t)ROWS * NE;
    float* WT4  = Pbuf + (size_t)ROWS * G3;

    wt_kernel<<<DE, 256, 0, stream>>>(Wi, WT4);
    proj_kernel<<<ROWS / RPB, 256, 0, stream>>>(h_seq, ek, WT4, bi, Wih, Pbuf, wbuf);
    scan_kernel<<<B_ * NE, 192, 0, stream>>>(Pbuf, wbuf, Whh, bih, bhh, e0, out, write1);

    if (!write1) {
        copy_kernel<<<2048, 256, 0, stream>>>((const float4*)out,
                                              (float4*)(out + OUT1OFF), OUT1OFF / 4);
    }
}

// Round 9
// 1364.017 us; speedup vs baseline: 1.0161x; 1.0151x over previous
//
#include <hip/hip_runtime.h>
#include <hip/hip_bf16.h>

// EntityTable: B=16,T=2048,D=1024,N_E=8,D_E=64
// Phase A (parallel): hp = h@Wi^T + bi ; logits = h@ek^T/32 ; w = softmax(logits)
//                     P  = W_ih @ hp   (entity-independent input-gate projection)
// Phase B (sequential scan over T): per cell (b,n):
//   gx_k = w*P_k + b_ih_k ; gh_k = W_hh[k]·s + b_hh_k
//   r=sig(gx0+gh0) z=sig(gx1+gh1) n=tanh(gx2 + r*gh2) ; s' = (1-z)n + z s
//
// Round-9 scan: r8 + amdgpu_waves_per_eu(1,1). r7/r8's VGPR_Count=48 showed
// the backend caps registers for DEFAULT occupancy (8 waves/EU for 192-thr
// blocks) and sinks the loop-invariant weight loads into the loop (per-step
// L1 refetch + vmcnt drains pulling prefetch latency onto the serial path).
// waves_per_eu(1,1) raises the budget to ~512 VGPRs so the 64 weight VGPRs
// stay resident. Occupancy is 1 block/CU by construction - the cap is free.

constexpr int B_  = 16;
constexpr int T_  = 2048;
constexpr int D_  = 1024;
constexpr int NE  = 8;
constexpr int DE  = 64;
constexpr int G3  = 192;            // 3*DE
constexpr int ROWS = B_ * T_;       // 32768
constexpr int OUT1OFF = ROWS * NE * DE;  // 16777216

typedef __attribute__((ext_vector_type(2))) float f32x2;
typedef __attribute__((ext_vector_type(4))) float f32x4;

__device__ __forceinline__ void pkacc(f32x2& acc, f32x2 w, f32x2 s) {
    asm("v_pk_fma_f32 %0, %1, %2, %0" : "+v"(acc) : "v"(w), "v"(s));
}

// ---------------- Kernel T: transpose Wi -> WT4 ----------------
__global__ __launch_bounds__(256) void wt_kernel(
    const float* __restrict__ Wi, float* __restrict__ WT4)
{
    const int o  = blockIdx.x;     // 64 blocks
    const int dq = threadIdx.x;    // 256 threads
    const float4 v = *(const float4*)&Wi[o * D_ + dq * 4];
    *(float4*)&WT4[(dq * 64 + o) * 4] = v;
}

// ---------------- Kernel A: projection + routing + P ----------------
constexpr int RPB = 32;   // rows per block
constexpr int CH  = 128;  // K-chunk

__global__ __launch_bounds__(256) void proj_kernel(
    const float* __restrict__ h,   const float* __restrict__ ek,
    const float* __restrict__ WT4, const float* __restrict__ bi,
    const float* __restrict__ Wih,
    float* __restrict__ Pout, float* __restrict__ wout)
{
    __shared__ float hch[RPB][CH];   // 16 KB
    __shared__ float hp[RPB][DE];    // 8 KB
    __shared__ float lg[RPB][NE];    // 1 KB

    const int tid = threadIdx.x;
    const int brow = blockIdx.x * RPB;
    const int w = tid >> 6;          // wave 0..3
    const int o = tid & 63;          // lane = output index for hp
    const int n  = o & 7;            // entity for logit partial
    const int sl = o >> 3;           // K-slice for logit partial

    float acc[8], accl[8];
#pragma unroll
    for (int r = 0; r < 8; ++r) { acc[r] = 0.f; accl[r] = 0.f; }

    for (int kc = 0; kc < D_; kc += CH) {
        __syncthreads();
#pragma unroll
        for (int i = 0; i < 4; ++i) {
            int idx = tid + i * 256;
            int lr = idx >> 5;
            int c4 = (idx & 31) * 4;
            *(float4*)&hch[lr][c4] =
                *(const float4*)&h[(size_t)(brow + lr) * D_ + kc + c4];
        }
        __syncthreads();

        for (int d4 = 0; d4 < CH / 4; ++d4) {
            const float4 wt = *(const float4*)&WT4[((kc >> 2) + d4) * 256 + (o << 2)];
#pragma unroll
            for (int r = 0; r < 8; ++r) {
                const float4 h4 = *(const float4*)&hch[w * 8 + r][d4 * 4];
                acc[r] = fmaf(wt.x, h4.x,
                         fmaf(wt.y, h4.y,
                         fmaf(wt.z, h4.z,
                         fmaf(wt.w, h4.w, acc[r]))));
            }
        }
#pragma unroll
        for (int i4 = 0; i4 < 4; ++i4) {
            const int dl = sl * 16 + i4 * 4;
            const float4 e4 = *(const float4*)&ek[n * D_ + kc + dl];
#pragma unroll
            for (int r = 0; r < 8; ++r) {
                const float4 h4 = *(const float4*)&hch[w * 8 + r][dl];
                accl[r] = fmaf(e4.x, h4.x,
                          fmaf(e4.y, h4.y,
                          fmaf(e4.z, h4.z,
                          fmaf(e4.w, h4.w, accl[r]))));
            }
        }
    }

    const float biv = bi[o];
#pragma unroll
    for (int r = 0; r < 8; ++r) hp[w * 8 + r][o] = acc[r] + biv;

#pragma unroll
    for (int r = 0; r < 8; ++r) {
        accl[r] += __shfl_xor(accl[r], 8);
        accl[r] += __shfl_xor(accl[r], 16);
        accl[r] += __shfl_xor(accl[r], 32);
    }
    if (sl == 0) {
#pragma unroll
        for (int r = 0; r < 8; ++r) lg[w * 8 + r][n] = accl[r] * 0.03125f;
    }
    __syncthreads();

    if (tid < RPB) {
        const int lr = tid;
        float v[NE];
        float m = -1e30f;
#pragma unroll
        for (int e = 0; e < NE; ++e) { v[e] = lg[lr][e]; m = fmaxf(m, v[e]); }
        float s = 0.f;
#pragma unroll
        for (int e = 0; e < NE; ++e) { v[e] = __expf(v[e] - m); s += v[e]; }
        const float inv = 1.f / s;
#pragma unroll
        for (int e = 0; e < NE; ++e)
            wout[(size_t)(brow + lr) * NE + e] = v[e] * inv;
    }

    if (tid < G3) {
        const int k = tid;
        for (int lr0 = 0; lr0 < RPB; lr0 += 8) {
            float pacc[8];
#pragma unroll
            for (int r = 0; r < 8; ++r) pacc[r] = 0.f;
            for (int d4 = 0; d4 < DE / 4; ++d4) {
                const float4 wv = *(const float4*)&Wih[k * DE + d4 * 4];
#pragma unroll
                for (int r = 0; r < 8; ++r) {
                    const float4 h4 = *(const float4*)&hp[lr0 + r][d4 * 4];
                    pacc[r] = fmaf(wv.x, h4.x,
                              fmaf(wv.y, h4.y,
                              fmaf(wv.z, h4.z,
                              fmaf(wv.w, h4.w, pacc[r]))));
                }
            }
#pragma unroll
            for (int r = 0; r < 8; ++r)
                Pout[(size_t)(brow + lr0 + r) * G3 + k] = pacc[r];
        }
    }
}

// ---------------- Kernel B: 3-wave gate-split GRU scan (resident weights) ----------------
// 128 blocks x 192 threads. Wave wid owns gate wid (rows wid*64+j).
#define DW(q) f32x4 w##q = *(const f32x4*)&Whh[(size_t)base * 64 + 4 * (q)];
#define DW16() \
    DW(0)  DW(1)  DW(2)  DW(3)  DW(4)  DW(5)  DW(6)  DW(7) \
    DW(8)  DW(9)  DW(10) DW(11) DW(12) DW(13) DW(14) DW(15)

// keep-alive: pin each weight value (non-rematerializable)
#define KA(q) asm volatile("" : "+v"(w##q));
#define KA16() \
    KA(0)  KA(1)  KA(2)  KA(3)  KA(4)  KA(5)  KA(6)  KA(7) \
    KA(8)  KA(9)  KA(10) KA(11) KA(12) KA(13) KA(14) KA(15)

#define MACQ(q) { \
    const f32x4 s4 = *(const f32x4*)&s_own[wid][4 * (q)]; \
    pkacc(acc, w##q.lo, s4.lo); pkacc(acc, w##q.hi, s4.hi); }
#define MAC16() \
    MACQ(0)  MACQ(1)  MACQ(2)  MACQ(3)  MACQ(4)  MACQ(5)  MACQ(6)  MACQ(7) \
    MACQ(8)  MACQ(9)  MACQ(10) MACQ(11) MACQ(12) MACQ(13) MACQ(14) MACQ(15)

__global__ __launch_bounds__(192)
__attribute__((amdgpu_waves_per_eu(1, 1)))
void scan_kernel(
    const float* __restrict__ P,   const float* __restrict__ route,
    const float* __restrict__ Whh, const float* __restrict__ bih,
    const float* __restrict__ bhh, const float* __restrict__ e0,
    float* __restrict__ out, int write1)
{
    __shared__ __align__(16) float s_own[3][DE];   // per-wave private state copy
    __shared__ float ex[2][4][DE];                 // dbuf exchange {rr,zz,u,v}

    // XCD co-location (halves scan FETCH, time-neutral)
    const int g   = blockIdx.x;          // 0..127
    const int xcd = g & 7;
    const int ii  = g >> 3;              // 0..15
    const int b   = xcd + 8 * (ii & 1);
    const int n   = ii >> 1;
    const int tid = threadIdx.x;
    const int wid = tid >> 6;            // 0=r, 1=z, 2=n gate
    const int j   = tid & 63;
    const int base = wid * DE + j;       // this lane's gate row

    DW16()                               // 16 f32x4 = 64 VGPR weights
    KA16()                               // pin resident

    // biases: waves 0/1 use combined (bih+bhh); wave 2 keeps them split
    const float Bc   = bih[base] + bhh[base];
    const float bin_ = bih[base];        // wave 2 only
    const float bhn_ = bhh[base];        // wave 2 only

    const size_t row0 = (size_t)b * T_;
    float s_reg = e0[n * DE + j];
    s_own[wid][j] = s_reg;               // own-wave write/read (lgkm-ordered)

    const float* Pb = P + row0 * G3 + base;   // this wave's gate rows, + t*G3
    const float* rb = route + row0 * NE + n;  // + t*NE
    float* op = out + row0 * (size_t)(NE * DE) + n * DE + j;

    // prefetch depth 2
    float p0 = Pb[0], p1 = Pb[G3];
    float wv0 = rb[0], wv1 = rb[NE];

    int buf = 0;

    for (int t = 0; t < T_; ++t) {
        const int tn = (t + 2 < T_) ? (t + 2) : t;     // clamp tail
        const float pnx  = Pb[(size_t)tn * G3];
        const float wnx  = rb[(size_t)tn * NE];

        // ---- this wave's gate dot over its private s copy ----
        f32x2 acc = {0.f, 0.f};
        MAC16()
        const float gh = acc.x + acc.y;
        const float gx = fmaf(wv0, p0, (wid == 2) ? bin_ : Bc);

        // ---- pre-barrier: waves 0/1 fold their sigmoid; wave 2 ships u,v ----
        if (wid == 2) {
            ex[buf][2][j] = gx;           // u = gx_n + b_ih,n
            ex[buf][3][j] = gh + bhn_;    // v = gh_n + b_hh,n
        } else {
            const float sg = __builtin_amdgcn_rcpf(1.f + __expf(-(gx + gh)));
            ex[buf][wid][j] = sg;         // rr (wid 0) / zz (wid 1)
        }

        asm volatile("s_waitcnt lgkmcnt(0)" ::: "memory");
        __builtin_amdgcn_s_barrier();

        // ---- redundant activation (all waves) ----
        const float rr = ex[buf][0][j];
        const float zz = ex[buf][1][j];
        const float u  = ex[buf][2][j];
        const float v  = ex[buf][3][j];
        const float x  = fmaf(rr, v, u);
        const float nn = fmaf(2.f, __builtin_amdgcn_rcpf(1.f + __expf(-2.f * x)), -1.f);
        const float snew = fmaf(zz, s_reg - nn, nn);   // (1-z)n + z s
        s_reg = snew;
        s_own[wid][j] = snew;             // own copy for next step's dot

        if (wid == 0) op[(size_t)t * (NE * DE)] = snew;
        else if (write1 && wid == 1) op[OUT1OFF + (size_t)t * (NE * DE)] = snew;

        p0 = p1; p1 = pnx; wv0 = wv1; wv1 = wnx;
        buf ^= 1;
    }
}

// ---------------- Kernel C: replicate out0 -> out1 (stash path) ----------------
__global__ __launch_bounds__(256) void copy_kernel(
    const float4* __restrict__ src, float4* __restrict__ dst, int n4)
{
    int i = blockIdx.x * 256 + threadIdx.x;
    const int stride = gridDim.x * 256;
    for (; i < n4; i += stride) dst[i] = src[i];
}

extern "C" void kernel_launch(void* const* d_in, const int* in_sizes, int n_in,
                              void* d_out, int out_size, void* d_ws, size_t ws_size,
                              hipStream_t stream) {
    const float* h_seq = (const float*)d_in[0];
    const float* ek    = (const float*)d_in[1];
    const float* Wi    = (const float*)d_in[2];
    const float* bi    = (const float*)d_in[3];
    const float* Wih   = (const float*)d_in[4];
    const float* Whh   = (const float*)d_in[5];
    const float* bih   = (const float*)d_in[6];
    const float* bhh   = (const float*)d_in[7];
    const float* e0    = (const float*)d_in[8];
    float* out = (float*)d_out;

    const size_t need = (size_t)ROWS * (G3 + NE) * sizeof(float)
                      + (size_t)DE * D_ * sizeof(float);  // ~26.5 MB
    float* wbuf;
    int write1;
    if (ws_size >= need) {
        wbuf = (float*)d_ws;
        write1 = 1;                    // scan writes both output copies
    } else {
        wbuf = out + OUT1OFF;          // stash in out1; copy at the end
        write1 = 0;
    }
    float* Pbuf = wbuf + (size_t)ROWS * NE;
    float* WT4  = Pbuf + (size_t)ROWS * G3;

    wt_kernel<<<DE, 256, 0, stream>>>(Wi, WT4);
    proj_kernel<<<ROWS / RPB, 256, 0, stream>>>(h_seq, ek, WT4, bi, Wih, Pbuf, wbuf);
    scan_kernel<<<B_ * NE, 192, 0, stream>>>(Pbuf, wbuf, Whh, bih, bhh, e0, out, write1);

    if (!write1) {
        copy_kernel<<<2048, 256, 0, stream>>>((const float4*)out,
                                              (float4*)(out + OUT1OFF), OUT1OFF / 4);
    }
}